// Round 3
// baseline (126.788 us; speedup 1.0000x reference)
//
#include <hip/hip_runtime.h>

#define B_SZ   32
#define T_LEN  160000
#define NFFT   1024
#define HOP    320
#define FRAMES 501
#define NBINS  513
#define PADL   512

#define MROWS_BF  1024                    // interleaved cos/sin rows staged as bf16 (bins 0..511)
#define XP_STRIDE 164864                  // padded per-batch xp length (elements)
#define WS_XP_OFF (MROWS_BF * NFFT)       // ushort-element offset of xp region in ws
#define XP_G8_PB  (XP_STRIDE / 8)         // 20608 8-elem groups per batch

// prep-kernel block ranges
#define PB_BASIS  512                     // basis convert (131072 thr x 8 elems)
#define PB_XP     2576                    // xp convert    (659456 thr x 8 elems)
#define PB_BIN512 4012                    // bin512        (16048 waves >= 16032 dots)
#define PREP_BLOCKS (PB_BASIS + PB_XP + PB_BIN512)

// K-trim: Hann window (WIN=800) is zero outside k in [112,912) -> basis cols
// there are exactly 0.0. Cover with 32-aligned range [96,928): 26 tiles of 32.
#define KT0  96
#define NKT  26

#define LBUF 12288                        // elems per LDS buffer: A 8192 + B 4096

typedef __bf16 bf16x8  __attribute__((ext_vector_type(8)));
typedef float  floatx4 __attribute__((ext_vector_type(4)));

__device__ __forceinline__ unsigned short f2bf(float f) {
    unsigned u = __builtin_bit_cast(unsigned, f);
    u += 0x7FFFu + ((u >> 16) & 1u);      // round-to-nearest-even
    return (unsigned short)(u >> 16);
}

__device__ __forceinline__ void gl_lds16(const void* g, void* l) {
    __builtin_amdgcn_global_load_lds(
        (const __attribute__((address_space(1))) unsigned int*)g,
        (__attribute__((address_space(3))) unsigned int*)l, 16, 0, 0);
}

// ---- fused prep (verified R5): basis->bf16 | x->padded bf16 xp | bin512 fp32 ----
__global__ void stft_prep(const float* __restrict__ x,
                          const float* __restrict__ basis,
                          unsigned short* __restrict__ basisb,
                          unsigned short* __restrict__ xpb,
                          float* __restrict__ out) {
    const int blk = blockIdx.x;
    const int tid = threadIdx.x;

    if (blk < PB_BASIS) {
        const int gid = blk * 256 + tid;          // 8 elems per thread, exact cover
        const int row = gid >> 7;                 // 0..1023
        const int col = (gid & 127) * 8;
        const int j = row >> 1, c = row & 1;
        const float* src = basis + (size_t)(j + c * NBINS) * NFFT + col;
        const float4 v0 = *(const float4*)(src);
        const float4 v1 = *(const float4*)(src + 4);
        ushort4 o0, o1;
        o0.x = f2bf(v0.x); o0.y = f2bf(v0.y); o0.z = f2bf(v0.z); o0.w = f2bf(v0.w);
        o1.x = f2bf(v1.x); o1.y = f2bf(v1.y); o1.z = f2bf(v1.z); o1.w = f2bf(v1.w);
        unsigned short* d = basisb + ((size_t)row << 10) + col;
        *(ushort4*)(d)     = o0;
        *(ushort4*)(d + 4) = o1;
    } else if (blk < PB_BASIS + PB_XP) {
        const int i   = (blk - PB_BASIS) * 256 + tid;   // 0..659455, exact cover
        const int b   = i / XP_G8_PB;
        const int pos = (i - b * XP_G8_PB) * 8;         // boundaries (512,160512) are %8==0
        ushort4 o0 = {0,0,0,0}, o1 = {0,0,0,0};
        if (pos >= PADL && pos < T_LEN + PADL) {
            const float* src = x + (size_t)b * T_LEN + (pos - PADL);
            const float4 v0 = *(const float4*)(src);
            const float4 v1 = *(const float4*)(src + 4);
            o0.x = f2bf(v0.x); o0.y = f2bf(v0.y); o0.z = f2bf(v0.z); o0.w = f2bf(v0.w);
            o1.x = f2bf(v1.x); o1.y = f2bf(v1.y); o1.z = f2bf(v1.z); o1.w = f2bf(v1.w);
        }
        unsigned short* d = xpb + (size_t)b * XP_STRIDE + pos;
        *(ushort4*)(d)     = o0;
        *(ushort4*)(d + 4) = o1;
    } else {
        const int lane = tid & 63;
        const int d    = (blk - PB_BASIS - PB_XP) * 4 + (tid >> 6);  // wave-dot id
        if (d >= B_SZ * FRAMES) return;                              // wave-uniform
        const int b = d / FRAMES;
        const int f = d - b * FRAMES;
        const float* br = basis + (size_t)512 * NFFT + lane * 16;
        const float* xb = x + (size_t)b * T_LEN;
        const int base = f * HOP - PADL + lane * 16;
        float sum = 0.f;
        #pragma unroll
        for (int c = 0; c < 4; ++c) {
            const int xi = base + c * 4;
            const float4 bv = *(const float4*)(br + c * 4);
            float4 v;
            if (xi >= 0 && xi + 3 < T_LEN) {
                v = *(const float4*)(xb + xi);
            } else {
                v.x = (xi + 0 >= 0 && xi + 0 < T_LEN) ? xb[xi + 0] : 0.f;
                v.y = (xi + 1 >= 0 && xi + 1 < T_LEN) ? xb[xi + 1] : 0.f;
                v.z = (xi + 2 >= 0 && xi + 2 < T_LEN) ? xb[xi + 2] : 0.f;
                v.w = (xi + 3 >= 0 && xi + 3 < T_LEN) ? xb[xi + 3] : 0.f;
            }
            sum += bv.x * v.x + bv.y * v.y + bv.z * v.z + bv.w * v.w;
        }
        #pragma unroll
        for (int off = 32; off >= 1; off >>= 1) sum += __shfl_down(sum, off);
        if (lane == 0) {
            float2 val; val.x = sum; val.y = 0.f;
            *(float2*)(out + (((size_t)b * NBINS + 512) * FRAMES + f) * 2) = val;
        }
    }
}

// ---- MFMA GEMM v4: 256(M) x 128(F) tile, BK=32, 8 waves (4M x 2N -> 64x64/wave).
// TLP-first design: 72 KB LDS (3 rotating buffers) -> 2 independent blocks/CU
// (16 waves, 4/SIMD) so one block's read/stage/sync region overlaps the other's
// MFMA region. One barrier per phase; distance-2 prefetch into a 3rd buffer
// (no WAR with the buffer being read); counted vmcnt(3), never 0 in-loop.
// K trimmed to [96,928) (window support) -> 26 tiles, -19% MFMA, bit-identical.
// Ledger: phase(t) = [barrier][stage tile t+2 -> buf (t+2)%3 : 3 loads]
//   [8 ds_read_b128 of tile t from buf t%3][16 MFMA][vmcnt(3)].
// vmcnt(3) at end of phase t-1 leaves only phase-(t-1)'s 3 stage-loads pending,
// so tile t (staged in phase t-2) is resident; each wave passes barrier(t) only
// after its own vmcnt(3), so post-barrier ALL waves' tile-t stages are complete.
// WAR: stage(t+2) overwrites buf last read in phase t-1; those reads drained
// (lgkm) before each wave's MFMA, hence before its barrier(t) arrival.
__launch_bounds__(512, 4)
__global__ void stft_mfma_kernel(const unsigned short* __restrict__ basisb,
                                 const unsigned short* __restrict__ xpb,
                                 float* __restrict__ out) {
    __shared__ unsigned short lds[3 * LBUF];   // 72 KB: per buf A[0..8191], B[8192..12287]

    const int tid  = threadIdx.x;
    const int lane = tid & 63;
    const int w    = tid >> 6;        // wave 0..7
    const int wm   = w & 3;           // 64-row quarter of 256
    const int wn   = w >> 2;          // 64-frame half of 128
    const int r0   = lane & 15;
    const int quad = lane >> 4;
    // swizzled 16B-slot within a 64-B row: slot = quad ^ ((row>>1)&3)
    const int ce   = (quad ^ ((r0 >> 1) & 3)) * 8;

    const int b   = blockIdx.x;                 // batch fastest -> XCD = b%8
    const int fg0 = blockIdx.y * 128;           // frame tile base (0..384)
    const int mg0 = blockIdx.z * 256;           // row tile base (0..768)
    const unsigned short* xpbb = xpb + (size_t)b * XP_STRIDE;

    // staging: A 256x32 (16KB, 2 loads/thr), B 128x32 (8KB, 1 load/thr).
    // LDS dest linear; global source column pre-swizzled (same involution as reads).
    const int i0 = tid, i1 = 512 + tid;
    const int rowA0 = i0 >> 2, rowA1 = i1 >> 2;        // 0..127, 128..255
    const int rowB  = tid >> 2;                        // 0..127
    const int csA0 = ((i0 & 3) ^ ((rowA0 >> 1) & 3)) * 8;
    const int csA1 = ((i1 & 3) ^ ((rowA1 >> 1) & 3)) * 8;
    const int csB  = ((tid & 3) ^ ((rowB >> 1) & 3)) * 8;
    const unsigned short* arow0 = basisb + ((size_t)(mg0 + rowA0) << 10) + csA0;
    const unsigned short* arow1 = basisb + ((size_t)(mg0 + rowA1) << 10) + csA1;
    const unsigned short* brow0 = xpbb + (size_t)(fg0 + rowB) * HOP + csB;

#define STAGE(kk, sto) do {                                         \
    const int ko_ = KT0 + (kk) * 32;                                \
    gl_lds16(arow0 + ko_, &lds[(sto) + i0 * 8]);                    \
    gl_lds16(arow1 + ko_, &lds[(sto) + i1 * 8]);                    \
    gl_lds16(brow0 + ko_, &lds[(sto) + 8192 + tid * 8]);            \
} while (0)

    floatx4 acc[4][4] = {};

    // prologue: tiles 0,1 -> bufs 0,1; vmcnt(3) => my tile-0 stages landed
    STAGE(0, 0); STAGE(1, LBUF);
    asm volatile("s_waitcnt vmcnt(3)" ::: "memory");

    int rdo = 0, sto = 2 * LBUF;
    #pragma unroll 1
    for (int t = 0; t < NKT; ++t) {
        __builtin_amdgcn_s_barrier();
        int kk = t + 2; if (kk >= NKT) kk -= NKT;   // tail wraps: valid addrs, never read
        STAGE(kk, sto);

        bf16x8 af[4], bf[4];
        const unsigned short* pa = &lds[rdo + (wm * 64 + r0) * 32 + ce];
        const unsigned short* pb = &lds[rdo + 8192 + (wn * 64 + r0) * 32 + ce];
        #pragma unroll
        for (int mt = 0; mt < 4; ++mt) af[mt] = *(const bf16x8*)(pa + mt * 512);
        #pragma unroll
        for (int nt = 0; nt < 4; ++nt) bf[nt] = *(const bf16x8*)(pb + nt * 512);

        __builtin_amdgcn_s_setprio(1);
        #pragma unroll
        for (int mt = 0; mt < 4; ++mt)
            #pragma unroll
            for (int nt = 0; nt < 4; ++nt)
                acc[mt][nt] = __builtin_amdgcn_mfma_f32_16x16x32_bf16(
                    af[mt], bf[nt], acc[mt][nt], 0, 0, 0);
        __builtin_amdgcn_s_setprio(0);

        asm volatile("s_waitcnt vmcnt(3)" ::: "memory");
        rdo += LBUF; if (rdo == 3 * LBUF) rdo = 0;
        sto += LBUF; if (sto == 3 * LBUF) sto = 0;
    }
    // drain wrap-around garbage LDS-DMA before LDS is freed
    asm volatile("s_waitcnt vmcnt(0)" ::: "memory");

    // epilogue: rows are interleaved (cos,sin) pairs -> coalesced float2 stores
    const int mb = mg0 + wm * 64 + quad * 4;      // even
    const int fb = fg0 + wn * 64 + r0;
    #pragma unroll
    for (int nt = 0; nt < 4; ++nt) {
        const int f = fb + nt * 16;
        if (f >= FRAMES) continue;
        #pragma unroll
        for (int mt = 0; mt < 4; ++mt) {
            const int mrow = mb + mt * 16;
            const floatx4 v = acc[mt][nt];
            #pragma unroll
            for (int p = 0; p < 2; ++p) {
                const int bin = (mrow + 2 * p) >> 1;
                float2 val;
                val.x = v[2 * p];      // cos
                val.y = v[2 * p + 1];  // sin
                *(float2*)(out + (((size_t)b * NBINS + bin) * FRAMES + f) * 2) = val;
            }
        }
    }
#undef STAGE
}

extern "C" void kernel_launch(void* const* d_in, const int* in_sizes, int n_in,
                              void* d_out, int out_size, void* d_ws, size_t ws_size,
                              hipStream_t stream) {
    const float* x     = (const float*)d_in[0];
    const float* basis = (const float*)d_in[1];
    float* out         = (float*)d_out;

    unsigned short* basis_bf = (unsigned short*)d_ws;
    unsigned short* xp_bf    = (unsigned short*)d_ws + WS_XP_OFF;

    stft_prep<<<dim3(PREP_BLOCKS), dim3(256), 0, stream>>>(x, basis, basis_bf, xp_bf, out);

    // batch fastest -> XCD = b%8 (per-XCD: full A 2MB + 4 batches' xp 1.3MB < L2).
    // 512 blocks, 72KB LDS -> 2 blocks/CU co-resident (16 waves/CU).
    dim3 grid(B_SZ, 4, 4);   // batches x 4 frame-tiles(128) x 4 row-tiles(256)
    stft_mfma_kernel<<<grid, dim3(512), 0, stream>>>(basis_bf, xp_bf, out);
}